// Round 3
// baseline (283.843 us; speedup 1.0000x reference)
//
#include <hip/hip_runtime.h>

#define N 256
#define C 128
#define H 4
#define D 32
#define NP (N*N)            // 65536 pairs
#define LN_EPS 1e-5f

#define PSTR 264            // P LDS row stride (ushorts), 16B-aligned pad
#define LOG2E 1.4426950408889634f

using f32x4 = __attribute__((ext_vector_type(4))) float;
using bf8   = __attribute__((ext_vector_type(8))) short;   // 8 x bf16 (4 VGPRs)

__device__ __forceinline__ float bf2f(ushort u) {
    union { uint u; float f; } v; v.u = ((uint)u) << 16; return v.f;
}
__device__ __forceinline__ ushort f2bf(float f) {           // RNE
    union { float f; uint u; } v; v.f = f;
    uint u = v.u;
    u += 0x7fffu + ((u >> 16) & 1u);
    return (ushort)(u >> 16);
}
__device__ __forceinline__ ushort f2bf_trunc(float f) {     // truncate (1 VALU op)
    union { float f; uint u; } v; v.f = f;
    return (ushort)(v.u >> 16);
}

// ---------------------------------------------------------------- weights
// q-scale folds 1/sqrt(D) AND log2e (softmax later uses exp2 directly)
__global__ __launch_bounds__(256) void prep_weights(
    const float* __restrict__ wq, const float* __restrict__ wk,
    const float* __restrict__ wv, const float* __restrict__ wg,
    const float* __restrict__ wb, const float* __restrict__ wo,
    ushort* __restrict__ Wcat, ushort* __restrict__ Wb, ushort* __restrict__ Wo)
{
    int t = blockIdx.x * 256 + threadIdx.x;    // 65536 threads
    const float scale = 0.17677669529663689f * LOG2E;
    float v;
    if (t < 16384)       v = wq[t] * scale;
    else if (t < 32768)  v = wk[t - 16384];
    else if (t < 49152)  v = wv[t - 32768];
    else                 v = wg[t - 49152];
    Wcat[t] = f2bf(v);
    if (t < 16384) Wo[t] = f2bf(wo[t]);
    if (t < 512)   Wb[t] = f2bf(wb[t]);
}

// ---------------------------------------------------------------- layernorm
__global__ __launch_bounds__(256) void ln_kernel(
    const float* __restrict__ x, const float* __restrict__ lnw,
    const float* __restrict__ lnb, ushort* __restrict__ xn)
{
    int wave = threadIdx.x >> 6, lane = threadIdx.x & 63;
    int p = blockIdx.x * 4 + wave;
    const float* xp = x + (size_t)p * C;
    float a0 = xp[lane], a1 = xp[lane + 64];
    float s = a0 + a1, ss = a0 * a0 + a1 * a1;
    #pragma unroll
    for (int m = 1; m < 64; m <<= 1) {
        s  += __shfl_xor(s, m, 64);
        ss += __shfl_xor(ss, m, 64);
    }
    float mean = s * (1.f / 128.f);
    float var  = ss * (1.f / 128.f) - mean * mean;
    float rstd = rsqrtf(var + LN_EPS);
    ushort* op = xn + (size_t)p * C;
    op[lane]      = f2bf((a0 - mean) * rstd * lnw[lane]      + lnb[lane]);
    op[lane + 64] = f2bf((a1 - mean) * rstd * lnw[lane + 64] + lnb[lane + 64]);
}

// ---------------------------------------------------------------- triangle bias
// Output: bf16 * LOG2E, pre-permuted into the attn fragment layout (see attn).
__global__ __launch_bounds__(256) void tri_kernel(
    const ushort* __restrict__ xn, const ushort* __restrict__ Wb,
    ushort* __restrict__ tri_p)
{
    __shared__ float wb[512];
    int t = threadIdx.x;
    wb[t]       = bf2f(Wb[t]);
    wb[t + 256] = bf2f(Wb[t + 256]);
    __syncthreads();
    int p = blockIdx.x * 256 + t;
    const ushort* xp = xn + (size_t)p * C;
    float acc0 = 0, acc1 = 0, acc2 = 0, acc3 = 0;
    #pragma unroll
    for (int c8 = 0; c8 < 16; c8++) {
        uint4 pk = ((const uint4*)xp)[c8];
        const ushort* u = (const ushort*)&pk;
        #pragma unroll
        for (int j = 0; j < 8; j++) {
            float xv = bf2f(u[j]);
            int c = c8 * 8 + j;
            acc0 += xv * wb[c];
            acc1 += xv * wb[128 + c];
            acc2 += xv * wb[256 + c];
            acc3 += xv * wb[384 + c];
        }
    }
    int q = p >> 8, k = p & 255;
    int qc = q >> 4, quad = (q >> 2) & 3, r = q & 3;
    int n = k >> 4, lrow = k & 15;
    int lane = quad * 16 + lrow;
    int v = n * 4 + r, j = v >> 3, m = v & 7;
    int base = ((qc * 8 + j) * 64 + lane) * 8 + m;
    tri_p[base]             = f2bf(acc0 * LOG2E);
    tri_p[65536 + base]     = f2bf(acc1 * LOG2E);
    tri_p[2 * 65536 + base] = f2bf(acc2 * LOG2E);
    tri_p[3 * 65536 + base] = f2bf(acc3 * LOG2E);
}

// ---------------------------------------------------------------- QKVG projection GEMM
// [65536,512] = Xn[65536,128] @ Wcat[512,128]^T.
// A-tile (128 rows) staged ONCE in LDS; nt=0..3 loop inside block, B-fragments
// straight from global (Wcat 128 KB, L2-resident). nt: 0=q 1=k 2=v(->vbT) 3=gate.
__global__ __launch_bounds__(256, 4) void proj_gemm(
    const ushort* __restrict__ xn, const ushort* __restrict__ Wcat,
    const float* __restrict__ bg,
    ushort* __restrict__ qb, ushort* __restrict__ kb,
    ushort* __restrict__ vbT, ushort* __restrict__ gate)
{
    __shared__ ushort At[128 * 128];   // 32 KB
    int mt = blockIdx.x;               // 0..511
    int t  = threadIdx.x;

    const uint4* Ag = (const uint4*)(xn + (size_t)mt * 128 * C);
    #pragma unroll
    for (int ii = 0; ii < 8; ii++) {
        int idx = t + ii * 256;
        ((uint4*)At)[idx] = Ag[idx];
    }
    __syncthreads();

    int wave = t >> 6, lane = t & 63;
    int lrow = lane & 15, quad = lane >> 4;
    int wr = wave >> 1, wc = wave & 1;
    int i_row = mt >> 1;               // pair-row i (128 | 256)

    #pragma unroll 1
    for (int nt = 0; nt < 4; nt++) {
        f32x4 acc[4][4];
        #pragma unroll
        for (int mi = 0; mi < 4; mi++)
            #pragma unroll
            for (int ni = 0; ni < 4; ni++) acc[mi][ni] = (f32x4){0.f, 0.f, 0.f, 0.f};

        const ushort* Wbase = Wcat + (size_t)(nt * 128 + wc * 64) * C + quad * 8;
        #pragma unroll
        for (int ks = 0; ks < 4; ks++) {
            bf8 a[4], b[4];
            #pragma unroll
            for (int mi = 0; mi < 4; mi++)
                a[mi] = *(const bf8*)&At[(wr * 64 + mi * 16 + lrow) * 128 + ks * 32 + quad * 8];
            #pragma unroll
            for (int ni = 0; ni < 4; ni++)
                b[ni] = *(const bf8*)(Wbase + (size_t)(ni * 16 + lrow) * C + ks * 32);
            #pragma unroll
            for (int mi = 0; mi < 4; mi++)
                #pragma unroll
                for (int ni = 0; ni < 4; ni++)
                    acc[mi][ni] = __builtin_amdgcn_mfma_f32_16x16x32_bf16(a[mi], b[ni], acc[mi][ni], 0, 0, 0);
        }

        if (nt == 2) {
            // V: write transposed vbT[((i*H+h)*D + d) * N + key], 8B ushort4 stores
            #pragma unroll
            for (int mi = 0; mi < 4; mi++) {
                int j0 = (mt & 1) * 128 + wr * 64 + mi * 16 + quad * 4;   // key base
                #pragma unroll
                for (int ni = 0; ni < 4; ni++) {
                    int col = wc * 64 + ni * 16 + lrow;   // h*D+d
                    ushort4 pk;
                    pk.x = f2bf(acc[mi][ni][0]);
                    pk.y = f2bf(acc[mi][ni][1]);
                    pk.z = f2bf(acc[mi][ni][2]);
                    pk.w = f2bf(acc[mi][ni][3]);
                    *(ushort4*)&vbT[((size_t)(i_row * H) * D + col) * N + j0] = pk;
                }
            }
        } else {
            ushort* dst = (nt == 0) ? qb : (nt == 1) ? kb : gate;
            bool gated = (nt == 3);
            #pragma unroll
            for (int mi = 0; mi < 4; mi++) {
                #pragma unroll
                for (int ni = 0; ni < 4; ni++) {
                    int col = wc * 64 + ni * 16 + lrow;
                    #pragma unroll
                    for (int r = 0; r < 4; r++) {
                        int row = mt * 128 + wr * 64 + mi * 16 + quad * 4 + r;
                        float v = acc[mi][ni][r];
                        if (gated) v = 1.f / (1.f + __expf(-(v + bg[col])));
                        dst[(size_t)row * C + col] = f2bf(v);
                    }
                }
            }
        }
    }
}

// ---------------------------------------------------------------- attention
// grid (i=256, h=4) = 1024 blocks, 4 blocks/CU all-resident. LDS = P only
// (33.8 KB). Zero barriers: P is wave-private, K/V fragments stream from
// global (L1/L2-hot), V pre-transposed by proj_gemm. exp2-folded softmax.
__global__ __launch_bounds__(256, 4) void attn_kernel(
    const ushort* __restrict__ qb, const ushort* __restrict__ kb,
    const ushort* __restrict__ vbT, const ushort* __restrict__ tri_p,
    const float* __restrict__ mask, ushort* __restrict__ ob)
{
    __shared__ ushort Pl[4][16 * PSTR];   // 33.8 KB, wave-private 16-row P

    int i  = blockIdx.x;
    int h  = blockIdx.y;
    int t  = threadIdx.x;
    int wave = t >> 6, lane = t & 63;
    int lrow = lane & 15, quad = lane >> 4;

    // mask bias per lane's 16 key-columns (log2e-folded)
    float mb[16];
    #pragma unroll
    for (int n = 0; n < 16; n++)
        mb[n] = (1e9f * LOG2E) * (mask[i * N + n * 16 + lrow] - 1.0f);

    ushort* Pw = &Pl[wave][0];
    const ushort* trih  = tri_p + (size_t)h * 65536;
    const ushort* kbase = kb  + (size_t)(i * N) * C + h * D + quad * 8;
    const ushort* vbase = vbT + (size_t)((i * H + h) * D) * N + quad * 8;

    #pragma unroll 1
    for (int c = 0; c < 4; c++) {
        int qc = wave * 4 + c;
        bf8 aq = *(const bf8*)(qb + (size_t)(i * N + qc * 16 + lrow) * C + h * D + quad * 8);
        float sum[4] = {0.f, 0.f, 0.f, 0.f};

        #pragma unroll
        for (int half = 0; half < 2; half++) {
            f32x4 s8[8];
            #pragma unroll
            for (int n8 = 0; n8 < 8; n8++) {
                bf8 kf = *(const bf8*)(kbase + (size_t)((half * 8 + n8) * 16 + lrow) * C);
                s8[n8] = __builtin_amdgcn_mfma_f32_16x16x32_bf16(
                    aq, kf, (f32x4){0.f, 0.f, 0.f, 0.f}, 0, 0, 0);
            }
            // tri bias fragments: 4 x 16B vector loads (pre-permuted layout)
            const ushort* tp = trih + ((size_t)(qc * 8 + half * 4) * 64 + lane) * 8;
            bf8 tf[4];
            #pragma unroll
            for (int jj = 0; jj < 4; jj++)
                tf[jj] = *(const bf8*)(tp + jj * 512);

            #pragma unroll
            for (int n8 = 0; n8 < 8; n8++) {
                int n = half * 8 + n8;
                #pragma unroll
                for (int r = 0; r < 4; r++) {
                    float tb = bf2f(((const ushort*)&tf[n8 >> 1])[((n8 & 1) << 2) + r]);
                    float e  = exp2f(s8[n8][r] + tb + mb[n]);   // all log2e-prefolded
                    sum[r]  += e;
                    Pw[(quad * 4 + r) * PSTR + n * 16 + lrow] = f2bf_trunc(e);
                }
            }
        }
        // row sums -> 1/sum
        #pragma unroll
        for (int r = 0; r < 4; r++) {
            float s = sum[r];
            s += __shfl_xor(s, 1, 64);
            s += __shfl_xor(s, 2, 64);
            s += __shfl_xor(s, 4, 64);
            s += __shfl_xor(s, 8, 64);
            sum[r] = 1.f / s;
        }
        // wave-private P: drain LDS writes, no block barrier needed
        __asm__ volatile("s_waitcnt lgkmcnt(0)" ::: "memory");

        f32x4 o[2];
        o[0] = (f32x4){0.f, 0.f, 0.f, 0.f};
        o[1] = (f32x4){0.f, 0.f, 0.f, 0.f};
        #pragma unroll
        for (int ks = 0; ks < 8; ks++) {
            bf8 ap = *(const bf8*)&Pw[lrow * PSTR + ks * 32 + quad * 8];
            #pragma unroll
            for (int nv = 0; nv < 2; nv++) {
                bf8 bv = *(const bf8*)(vbase + (size_t)(nv * 16 + lrow) * N + ks * 32);
                o[nv] = __builtin_amdgcn_mfma_f32_16x16x32_bf16(ap, bv, o[nv], 0, 0, 0);
            }
        }
        #pragma unroll
        for (int nv = 0; nv < 2; nv++) {
            int d = nv * 16 + lrow;
            #pragma unroll
            for (int r = 0; r < 4; r++) {
                int qg = qc * 16 + quad * 4 + r;
                ob[(size_t)(i * N + qg) * C + h * D + d] = f2bf(o[nv][r] * sum[r]);
            }
        }
    }
}

// ---------------------------------------------------------------- gating + output proj
// out[65536,128] = (O .* gate)[65536,128] @ Wo[128,128]^T + b_o.
// A (gated O) staged in LDS; Wo fragments from global (32 KB, L2-resident).
__global__ __launch_bounds__(256, 4) void out_gemm(
    const ushort* __restrict__ ob, const ushort* __restrict__ gate,
    const ushort* __restrict__ Wo, const float* __restrict__ bo,
    float* __restrict__ out)
{
    __shared__ ushort At[128 * 128];   // 32 KB
    int mt = blockIdx.x;               // 0..511
    int t  = threadIdx.x;

    const uint4* Og = (const uint4*)(ob   + (size_t)mt * 128 * C);
    const uint4* Gg = (const uint4*)(gate + (size_t)mt * 128 * C);
    #pragma unroll
    for (int ii = 0; ii < 8; ii++) {
        int idx = t + ii * 256;
        uint4 o4 = Og[idx], g4 = Gg[idx], r4;
        const ushort* os = (const ushort*)&o4;
        const ushort* gs = (const ushort*)&g4;
        ushort* rs = (ushort*)&r4;
        #pragma unroll
        for (int j = 0; j < 8; j++) rs[j] = f2bf(bf2f(os[j]) * bf2f(gs[j]));
        ((uint4*)At)[idx] = r4;
    }
    __syncthreads();

    int wave = t >> 6, lane = t & 63;
    int lrow = lane & 15, quad = lane >> 4;
    int wr = wave >> 1, wc = wave & 1;

    f32x4 acc[4][4];
    #pragma unroll
    for (int mi = 0; mi < 4; mi++)
        #pragma unroll
        for (int ni = 0; ni < 4; ni++) acc[mi][ni] = (f32x4){0.f, 0.f, 0.f, 0.f};

    const ushort* Wbase = Wo + (size_t)(wc * 64) * C + quad * 8;
    #pragma unroll
    for (int ks = 0; ks < 4; ks++) {
        bf8 a[4], b[4];
        #pragma unroll
        for (int mi = 0; mi < 4; mi++)
            a[mi] = *(const bf8*)&At[(wr * 64 + mi * 16 + lrow) * 128 + ks * 32 + quad * 8];
        #pragma unroll
        for (int ni = 0; ni < 4; ni++)
            b[ni] = *(const bf8*)(Wbase + (size_t)(ni * 16 + lrow) * C + ks * 32);
        #pragma unroll
        for (int mi = 0; mi < 4; mi++)
            #pragma unroll
            for (int ni = 0; ni < 4; ni++)
                acc[mi][ni] = __builtin_amdgcn_mfma_f32_16x16x32_bf16(a[mi], b[ni], acc[mi][ni], 0, 0, 0);
    }

    #pragma unroll
    for (int mi = 0; mi < 4; mi++) {
        #pragma unroll
        for (int ni = 0; ni < 4; ni++) {
            int col = wc * 64 + ni * 16 + lrow;   // 0..127
            float bias = bo[col];
            #pragma unroll
            for (int r = 0; r < 4; r++) {
                int row = mt * 128 + wr * 64 + mi * 16 + quad * 4 + r;
                out[(size_t)row * C + col] = acc[mi][ni][r] + bias;
            }
        }
    }
}

// ---------------------------------------------------------------- launch
extern "C" void kernel_launch(void* const* d_in, const int* in_sizes, int n_in,
                              void* d_out, int out_size, void* d_ws, size_t ws_size,
                              hipStream_t stream)
{
    const float* x    = (const float*)d_in[0];
    const float* mask = (const float*)d_in[1];
    const float* lnw  = (const float*)d_in[2];
    const float* lnb  = (const float*)d_in[3];
    const float* wb   = (const float*)d_in[4];
    const float* wq   = (const float*)d_in[5];
    const float* wk   = (const float*)d_in[6];
    const float* wv   = (const float*)d_in[7];
    const float* wg   = (const float*)d_in[8];
    const float* bg   = (const float*)d_in[9];
    const float* wo   = (const float*)d_in[10];
    const float* bo   = (const float*)d_in[11];
    float* out = (float*)d_out;

    uintptr_t w = (uintptr_t)d_ws;
    ushort* xn    = (ushort*)w; w += (size_t)NP * C * 2;   // 16 MB
    ushort* qb    = (ushort*)w; w += (size_t)NP * C * 2;   // 16 MB
    ushort* kb    = (ushort*)w; w += (size_t)NP * C * 2;   // 16 MB
    ushort* vbT   = (ushort*)w; w += (size_t)NP * C * 2;   // 16 MB (transposed V)
    ushort* gate  = (ushort*)w; w += (size_t)NP * C * 2;   // 16 MB
    ushort* ob    = (ushort*)w; w += (size_t)NP * C * 2;   // 16 MB
    ushort* tri_p = (ushort*)w; w += (size_t)H * NP * 2;   // 0.5 MB
    ushort* Wcat  = (ushort*)w; w += 512 * 128 * 2;
    ushort* Wb    = (ushort*)w; w += 512 * 2;
    ushort* Wo    = (ushort*)w; w += 128 * 128 * 2;

    prep_weights<<<256, 256, 0, stream>>>(wq, wk, wv, wg, wb, wo, Wcat, Wb, Wo);
    ln_kernel<<<NP / 4, 256, 0, stream>>>(x, lnw, lnb, xn);
    tri_kernel<<<NP / 256, 256, 0, stream>>>(xn, Wb, tri_p);
    proj_gemm<<<NP / 128, 256, 0, stream>>>(xn, Wcat, bg, qb, kb, vbT, gate);
    attn_kernel<<<dim3(N, H), 256, 0, stream>>>(qb, kb, vbT, tri_p, mask, ob);
    out_gemm<<<NP / 128, 256, 0, stream>>>(ob, gate, Wo, bo, out);
}

// Round 4
// 196.484 us; speedup vs baseline: 1.4446x; 1.4446x over previous
//
#include <hip/hip_runtime.h>

#define N 256
#define C 128
#define H 4
#define D 32
#define NP (N*N)            // 65536 pairs
#define LN_EPS 1e-5f
#define LOG2E 1.4426950408889634f

using f32x4 = __attribute__((ext_vector_type(4))) float;
using bf8   = __attribute__((ext_vector_type(8))) short;   // 8 x bf16 (4 VGPRs)

__device__ __forceinline__ float bf2f(ushort u) {
    union { uint u; float f; } v; v.u = ((uint)u) << 16; return v.f;
}
__device__ __forceinline__ ushort f2bf(float f) {           // RNE
    union { float f; uint u; } v; v.f = f;
    uint u = v.u;
    u += 0x7fffu + ((u >> 16) & 1u);
    return (ushort)(u >> 16);
}
__device__ __forceinline__ ushort f2bf_trunc(float f) {     // truncate (1 VALU op)
    union { float f; uint u; } v; v.f = f;
    return (ushort)(v.u >> 16);
}

// ---------------------------------------------------------------- weights
// q-scale folds 1/sqrt(D) AND log2e (softmax uses exp2 directly)
__global__ __launch_bounds__(256) void prep_weights(
    const float* __restrict__ wq, const float* __restrict__ wk,
    const float* __restrict__ wv, const float* __restrict__ wg,
    const float* __restrict__ wb, const float* __restrict__ wo,
    ushort* __restrict__ Wcat, ushort* __restrict__ Wb, ushort* __restrict__ Wo)
{
    int t = blockIdx.x * 256 + threadIdx.x;    // 65536 threads
    const float scale = 0.17677669529663689f * LOG2E;
    float v;
    if (t < 16384)       v = wq[t] * scale;
    else if (t < 32768)  v = wk[t - 16384];
    else if (t < 49152)  v = wv[t - 32768];
    else                 v = wg[t - 49152];
    Wcat[t] = f2bf(v);
    if (t < 16384) Wo[t] = f2bf(wo[t]);
    if (t < 512)   Wb[t] = f2bf(wb[t]);
}

// ---------------------------------------------------------------- layernorm
__global__ __launch_bounds__(256) void ln_kernel(
    const float* __restrict__ x, const float* __restrict__ lnw,
    const float* __restrict__ lnb, ushort* __restrict__ xn)
{
    int wave = threadIdx.x >> 6, lane = threadIdx.x & 63;
    int p = blockIdx.x * 4 + wave;
    const float* xp = x + (size_t)p * C;
    float a0 = xp[lane], a1 = xp[lane + 64];
    float s = a0 + a1, ss = a0 * a0 + a1 * a1;
    #pragma unroll
    for (int m = 1; m < 64; m <<= 1) {
        s  += __shfl_xor(s, m, 64);
        ss += __shfl_xor(ss, m, 64);
    }
    float mean = s * (1.f / 128.f);
    float var  = ss * (1.f / 128.f) - mean * mean;
    float rstd = rsqrtf(var + LN_EPS);
    ushort* op = xn + (size_t)p * C;
    op[lane]      = f2bf((a0 - mean) * rstd * lnw[lane]      + lnb[lane]);
    op[lane + 64] = f2bf((a1 - mean) * rstd * lnw[lane + 64] + lnb[lane + 64]);
}

// ---------------------------------------------------------------- triangle bias
// Output: bf16 * LOG2E, pre-permuted into the attn fragment layout:
//   (h,q,k): qc=q>>4, quad=(q>>2)&3, r=q&3, n=k>>4, lrow=k&15
//   lane=quad*16+lrow, v=n*4+r, j=v>>3, m=v&7
//   idx = h*65536 + (((qc*8 + j)*64 + lane)*8 + m)
__global__ __launch_bounds__(256) void tri_kernel(
    const ushort* __restrict__ xn, const ushort* __restrict__ Wb,
    ushort* __restrict__ tri_p)
{
    __shared__ float wb[512];
    int t = threadIdx.x;
    wb[t]       = bf2f(Wb[t]);
    wb[t + 256] = bf2f(Wb[t + 256]);
    __syncthreads();
    int p = blockIdx.x * 256 + t;
    const ushort* xp = xn + (size_t)p * C;
    float acc0 = 0, acc1 = 0, acc2 = 0, acc3 = 0;
    #pragma unroll
    for (int c8 = 0; c8 < 16; c8++) {
        uint4 pk = ((const uint4*)xp)[c8];
        const ushort* u = (const ushort*)&pk;
        #pragma unroll
        for (int j = 0; j < 8; j++) {
            float xv = bf2f(u[j]);
            int c = c8 * 8 + j;
            acc0 += xv * wb[c];
            acc1 += xv * wb[128 + c];
            acc2 += xv * wb[256 + c];
            acc3 += xv * wb[384 + c];
        }
    }
    int q = p >> 8, k = p & 255;
    int qc = q >> 4, quad = (q >> 2) & 3, r = q & 3;
    int n = k >> 4, lrow = k & 15;
    int lane = quad * 16 + lrow;
    int v = n * 4 + r, j = v >> 3, m = v & 7;
    int base = ((qc * 8 + j) * 64 + lane) * 8 + m;
    tri_p[base]             = f2bf(acc0 * LOG2E);
    tri_p[65536 + base]     = f2bf(acc1 * LOG2E);
    tri_p[2 * 65536 + base] = f2bf(acc2 * LOG2E);
    tri_p[3 * 65536 + base] = f2bf(acc3 * LOG2E);
}

// ---------------------------------------------------------------- QKVG projection GEMM
// [65536,512] = Xn[65536,128] @ Wcat[512,128]^T, 128x128 tiles, grid (512,4).
// nt: 0=q(scaled) 1=k 2=v(-> vbT transposed, coalesced via LDS) 3=gate.
__global__ __launch_bounds__(256, 2) void proj_gemm(
    const ushort* __restrict__ xn, const ushort* __restrict__ Wcat,
    const float* __restrict__ bg,
    ushort* __restrict__ qb, ushort* __restrict__ kb,
    ushort* __restrict__ vbT, ushort* __restrict__ gate)
{
    __shared__ ushort At[128 * 128];   // 32 KB
    __shared__ ushort Bt[128 * 128];   // 32 KB (reused as transpose buf for nt==2)
    int mt = blockIdx.x;               // 0..511
    int nt = blockIdx.y;               // 0..3
    int t  = threadIdx.x;

    const uint4* Ag = (const uint4*)(xn   + (size_t)mt * 128 * C);
    const uint4* Bg = (const uint4*)(Wcat + (size_t)nt * 128 * C);
    #pragma unroll
    for (int ii = 0; ii < 8; ii++) {
        int idx = t + ii * 256;
        ((uint4*)At)[idx] = Ag[idx];
        ((uint4*)Bt)[idx] = Bg[idx];
    }
    __syncthreads();

    int wave = t >> 6, lane = t & 63;
    int lrow = lane & 15, quad = lane >> 4;
    int wr = wave >> 1, wc = wave & 1;

    f32x4 acc[4][4];
    #pragma unroll
    for (int mi = 0; mi < 4; mi++)
        #pragma unroll
        for (int ni = 0; ni < 4; ni++) acc[mi][ni] = (f32x4){0.f, 0.f, 0.f, 0.f};

    #pragma unroll
    for (int ks = 0; ks < 4; ks++) {
        bf8 a[4], b[4];
        #pragma unroll
        for (int mi = 0; mi < 4; mi++)
            a[mi] = *(const bf8*)&At[(wr * 64 + mi * 16 + lrow) * 128 + ks * 32 + quad * 8];
        #pragma unroll
        for (int ni = 0; ni < 4; ni++)
            b[ni] = *(const bf8*)&Bt[(wc * 64 + ni * 16 + lrow) * 128 + ks * 32 + quad * 8];
        #pragma unroll
        for (int mi = 0; mi < 4; mi++)
            #pragma unroll
            for (int ni = 0; ni < 4; ni++)
                acc[mi][ni] = __builtin_amdgcn_mfma_f32_16x16x32_bf16(a[mi], b[ni], acc[mi][ni], 0, 0, 0);
    }

    if (nt == 2) {
        // transpose through Bt (done with B), then coalesced 16B stores to vbT
        __syncthreads();
        #pragma unroll
        for (int mi = 0; mi < 4; mi++) {
            #pragma unroll
            for (int ni = 0; ni < 4; ni++) {
                int col = wc * 64 + ni * 16 + lrow;            // h*D+d, 0..127
                #pragma unroll
                for (int r = 0; r < 4; r++) {
                    int keyl = wr * 64 + mi * 16 + quad * 4 + r;   // 0..127
                    Bt[col * 128 + (keyl ^ (lrow << 3))] = f2bf(acc[mi][ni][r]);
                }
            }
        }
        __syncthreads();
        int i_row = mt >> 1;
        #pragma unroll
        for (int itr = 0; itr < 8; itr++) {
            int oidx = itr * 256 + t;          // 0..2047
            int col = oidx >> 4, kc = oidx & 15;
            bf8 val = *(const bf8*)&Bt[col * 128 + ((kc * 8) ^ ((col & 15) << 3))];
            *(bf8*)&vbT[(size_t)(i_row * 128 + col) * N + (mt & 1) * 128 + kc * 8] = val;
        }
    } else {
        ushort* dst = (nt == 0) ? qb : (nt == 1) ? kb : gate;
        bool gated = (nt == 3);
        #pragma unroll
        for (int mi = 0; mi < 4; mi++) {
            #pragma unroll
            for (int ni = 0; ni < 4; ni++) {
                int col = wc * 64 + ni * 16 + lrow;
                #pragma unroll
                for (int r = 0; r < 4; r++) {
                    int row = mt * 128 + wr * 64 + mi * 16 + quad * 4 + r;
                    float v = acc[mi][ni][r];
                    if (gated) v = 1.f / (1.f + __expf(-(v + bg[col])));
                    dst[(size_t)row * C + col] = f2bf(v);
                }
            }
        }
    }
}

// ---------------------------------------------------------------- attention
// grid (i=256, h=4), 512 threads = 8 waves, 2 q-chunks (16 rows) per wave.
// K/V staged coalesced into LDS in exact MFMA fragment order (conflict-free
// b128 reads). P per wave = one 128-key half (4 KB), flash-style two passes,
// O accumulated unnormalized. LDS = 64 KB -> 2 blocks/CU, 16 waves/CU,
// 1024 blocks = exactly 2 clean rounds.
__global__ __launch_bounds__(512, 4) void attn_kernel(
    const ushort* __restrict__ qb, const ushort* __restrict__ kb,
    const ushort* __restrict__ vbT, const ushort* __restrict__ tri_p,
    const float* __restrict__ mask, ushort* __restrict__ ob)
{
    __shared__ ushort Kf[8192];       // 16 KB: chunk c = kn*64+lane, 8 ushorts each
    __shared__ ushort Vf[8192];       // 16 KB: chunk c = nv*512+ks*64+lane, XOR-swizzled
    __shared__ ushort Pf[8][2048];    // 32 KB: per-wave 128-key half, A-frag order

    int i  = blockIdx.x;
    int h  = blockIdx.y;
    int t  = threadIdx.x;
    int wave = t >> 6, lane = t & 63;
    int lrow = lane & 15, quad = lane >> 4;

    // ---- stage K: global row-major (key, d) -> frag order, coalesced
    {
        const ushort* kt = kb + (size_t)(i * N) * C + h * D;
        #pragma unroll
        for (int it = 0; it < 2; it++) {
            int idx = it * 512 + t;                  // 0..1023
            int key = idx >> 2, d0 = (idx & 3) * 8;
            bf8 kv = *(const bf8*)(kt + (size_t)key * C + d0);
            int c = (idx >> 6) * 64 + (idx & 3) * 16 + ((idx >> 2) & 15);
            *(bf8*)&Kf[c * 8] = kv;
        }
    }
    // ---- stage V: vbT tile is contiguous 16 KB, coalesced; swizzled chunks
    {
        const ushort* vt = vbT + (size_t)((i * H + h) * D) * N;
        #pragma unroll
        for (int it = 0; it < 2; it++) {
            int idx = it * 512 + t;                  // 0..1023
            bf8 vv = *(const bf8*)(vt + idx * 8);
            int c = (idx >> 9) * 512 + ((idx >> 2) & 7) * 64 + (idx & 3) * 16 + ((idx >> 5) & 15);
            c ^= (c >> 6) & 7;
            *(bf8*)&Vf[c * 8] = vv;
        }
    }
    // mask bias per lane's 16 key-columns (log2e-folded)
    float mb[16];
    #pragma unroll
    for (int n = 0; n < 16; n++)
        mb[n] = (1e9f * LOG2E) * (mask[i * N + n * 16 + lrow] - 1.0f);
    __syncthreads();

    ushort* Pw = &Pf[wave][0];
    const ushort* trih = tri_p + (size_t)h * 65536;
    int pq = quad * 32 + (lrow & 7);       // P-write lane-invariant part
    int l3 = (lrow >> 3) & 1;

    #pragma unroll 1
    for (int cc = 0; cc < 2; cc++) {
        int qc = wave * 2 + cc;            // 0..15
        bf8 aq = *(const bf8*)(qb + (size_t)(i * N + qc * 16 + lrow) * C + h * D + quad * 8);
        float sum[4] = {0.f, 0.f, 0.f, 0.f};
        f32x4 o[2];
        o[0] = (f32x4){0.f, 0.f, 0.f, 0.f};
        o[1] = (f32x4){0.f, 0.f, 0.f, 0.f};

        #pragma unroll
        for (int half = 0; half < 2; half++) {
            // ---- S = Q K^T for 128 keys (8 MFMAs, K frags conflict-free from LDS)
            f32x4 s8[8];
            #pragma unroll
            for (int n8 = 0; n8 < 8; n8++) {
                bf8 kf = *(const bf8*)&Kf[((half * 8 + n8) * 64 + lane) * 8];
                s8[n8] = __builtin_amdgcn_mfma_f32_16x16x32_bf16(
                    aq, kf, (f32x4){0.f, 0.f, 0.f, 0.f}, 0, 0, 0);
            }
            // tri bias fragments: 4 x 16B coalesced loads (pre-permuted layout)
            const ushort* tp = trih + ((size_t)(qc * 8 + half * 4) * 64 + lane) * 8;
            bf8 tf[4];
            #pragma unroll
            for (int jj = 0; jj < 4; jj++)
                tf[jj] = *(const bf8*)(tp + jj * 512);

            // ---- exp2 softmax (no max-sub; logits tiny) + P write (A-frag order)
            #pragma unroll
            for (int n8 = 0; n8 < 8; n8++) {
                int pa = (n8 >> 1) * 512 + (((n8 << 1) + l3) & 3) * 128 + pq;
                #pragma unroll
                for (int r = 0; r < 4; r++) {
                    float tb = bf2f(((const ushort*)&tf[n8 >> 1])[((n8 & 1) << 2) + r]);
                    float e  = exp2f(s8[n8][r] + tb + mb[half * 8 + n8]);
                    sum[r]  += e;
                    Pw[pa + r * 8] = f2bf_trunc(e);
                }
            }
            // drain wave-private P writes (also guarantees prior P reads done)
            __asm__ volatile("s_waitcnt lgkmcnt(0)" ::: "memory");

            // ---- O += P V_half (K-dim 128 = 4 ks steps)
            #pragma unroll
            for (int ks = 0; ks < 4; ks++) {
                bf8 ap = *(const bf8*)&Pw[(ks * 64 + lane) * 8];
                int ksg = half * 4 + ks;
                #pragma unroll
                for (int nv = 0; nv < 2; nv++) {
                    int c = nv * 512 + ksg * 64 + (lane ^ (ksg & 7));
                    bf8 bv = *(const bf8*)&Vf[c * 8];
                    o[nv] = __builtin_amdgcn_mfma_f32_16x16x32_bf16(ap, bv, o[nv], 0, 0, 0);
                }
            }
        }
        // row sums -> 1/sum, normalize at epilogue
        #pragma unroll
        for (int r = 0; r < 4; r++) {
            float s = sum[r];
            s += __shfl_xor(s, 1, 64);
            s += __shfl_xor(s, 2, 64);
            s += __shfl_xor(s, 4, 64);
            s += __shfl_xor(s, 8, 64);
            sum[r] = 1.f / s;
        }
        #pragma unroll
        for (int nv = 0; nv < 2; nv++) {
            int d = nv * 16 + lrow;
            #pragma unroll
            for (int r = 0; r < 4; r++) {
                int qg = qc * 16 + quad * 4 + r;
                ob[(size_t)(i * N + qg) * C + h * D + d] = f2bf(o[nv][r] * sum[r]);
            }
        }
    }
}

// ---------------------------------------------------------------- gating + output proj
// out[65536,128] = (O .* gate)[65536,128] @ Wo[128,128]^T + b_o, 128x128 tiles
__global__ __launch_bounds__(256, 2) void out_gemm(
    const ushort* __restrict__ ob, const ushort* __restrict__ gate,
    const ushort* __restrict__ Wo, const float* __restrict__ bo,
    float* __restrict__ out)
{
    __shared__ ushort At[128 * 128];
    __shared__ ushort Bt[128 * 128];
    int mt = blockIdx.x;     // 0..511
    int t  = threadIdx.x;

    const uint4* Og = (const uint4*)(ob   + (size_t)mt * 128 * C);
    const uint4* Gg = (const uint4*)(gate + (size_t)mt * 128 * C);
    const uint4* Bg = (const uint4*)Wo;
    #pragma unroll
    for (int ii = 0; ii < 8; ii++) {
        int idx = t + ii * 256;
        uint4 o4 = Og[idx], g4 = Gg[idx], r4;
        const ushort* os = (const ushort*)&o4;
        const ushort* gs = (const ushort*)&g4;
        ushort* rs = (ushort*)&r4;
        #pragma unroll
        for (int j = 0; j < 8; j++) rs[j] = f2bf(bf2f(os[j]) * bf2f(gs[j]));
        ((uint4*)At)[idx] = r4;
        ((uint4*)Bt)[idx] = Bg[idx];
    }
    __syncthreads();

    int wave = t >> 6, lane = t & 63;
    int lrow = lane & 15, quad = lane >> 4;
    int wr = wave >> 1, wc = wave & 1;

    f32x4 acc[4][4];
    #pragma unroll
    for (int mi = 0; mi < 4; mi++)
        #pragma unroll
        for (int ni = 0; ni < 4; ni++) acc[mi][ni] = (f32x4){0.f, 0.f, 0.f, 0.f};

    #pragma unroll
    for (int ks = 0; ks < 4; ks++) {
        bf8 a[4], b[4];
        #pragma unroll
        for (int mi = 0; mi < 4; mi++)
            a[mi] = *(const bf8*)&At[(wr * 64 + mi * 16 + lrow) * 128 + ks * 32 + quad * 8];
        #pragma unroll
        for (int ni = 0; ni < 4; ni++)
            b[ni] = *(const bf8*)&Bt[(wc * 64 + ni * 16 + lrow) * 128 + ks * 32 + quad * 8];
        #pragma unroll
        for (int mi = 0; mi < 4; mi++)
            #pragma unroll
            for (int ni = 0; ni < 4; ni++)
                acc[mi][ni] = __builtin_amdgcn_mfma_f32_16x16x32_bf16(a[mi], b[ni], acc[mi][ni], 0, 0, 0);
    }

    #pragma unroll
    for (int mi = 0; mi < 4; mi++) {
        #pragma unroll
        for (int ni = 0; ni < 4; ni++) {
            int col = wc * 64 + ni * 16 + lrow;   // 0..127
            float bias = bo[col];
            #pragma unroll
            for (int r = 0; r < 4; r++) {
                int row = mt * 128 + wr * 64 + mi * 16 + quad * 4 + r;
                out[(size_t)row * C + col] = acc[mi][ni][r] + bias;
            }
        }
    }
}

// ---------------------------------------------------------------- launch
extern "C" void kernel_launch(void* const* d_in, const int* in_sizes, int n_in,
                              void* d_out, int out_size, void* d_ws, size_t ws_size,
                              hipStream_t stream)
{
    const float* x    = (const float*)d_in[0];
    const float* mask = (const float*)d_in[1];
    const float* lnw  = (const float*)d_in[2];
    const float* lnb  = (const float*)d_in[3];
    const float* wb   = (const float*)d_in[4];
    const float* wq   = (const float*)d_in[5];
    const float* wk   = (const float*)d_in[6];
    const float* wv   = (const float*)d_in[7];
    const float* wg   = (const float*)d_in[8];
    const float* bg   = (const float*)d_in[9];
    const float* wo   = (const float*)d_in[10];
    const float* bo   = (const float*)d_in[11];
    float* out = (float*)d_out;

    uintptr_t w = (uintptr_t)d_ws;
    ushort* xn    = (ushort*)w; w += (size_t)NP * C * 2;   // 16 MB
    ushort* qb    = (ushort*)w; w += (size_t)NP * C * 2;   // 16 MB
    ushort* kb    = (ushort*)w; w += (size_t)NP * C * 2;   // 16 MB
    ushort* vbT   = (ushort*)w; w += (size_t)NP * C * 2;   // 16 MB (transposed V)
    ushort* gate  = (ushort*)w; w += (size_t)NP * C * 2;   // 16 MB
    ushort* ob    = (ushort*)w; w += (size_t)NP * C * 2;   // 16 MB
    ushort* tri_p = (ushort*)w; w += (size_t)H * NP * 2;   // 0.5 MB
    ushort* Wcat  = (ushort*)w; w += 512 * 128 * 2;
    ushort* Wb    = (ushort*)w; w += 512 * 2;
    ushort* Wo    = (ushort*)w; w += 128 * 128 * 2;

    prep_weights<<<256, 256, 0, stream>>>(wq, wk, wv, wg, wb, wo, Wcat, Wb, Wo);
    ln_kernel<<<NP / 4, 256, 0, stream>>>(x, lnw, lnb, xn);
    tri_kernel<<<NP / 256, 256, 0, stream>>>(xn, Wb, tri_p);
    proj_gemm<<<dim3(NP / 128, 4), 256, 0, stream>>>(xn, Wcat, bg, qb, kb, vbT, gate);
    attn_kernel<<<dim3(N, H), 512, 0, stream>>>(qb, kb, vbT, tri_p, mask, ob);
    out_gemm<<<NP / 128, 256, 0, stream>>>(ob, gate, Wo, bo, out);
}

// Round 5
// 181.661 us; speedup vs baseline: 1.5625x; 1.0816x over previous
//
#include <hip/hip_runtime.h>

#define N 256
#define C 128
#define H 4
#define D 32
#define NP (N*N)            // 65536 pairs
#define LN_EPS 1e-5f
#define LOG2E 1.4426950408889634f

using f32x4 = __attribute__((ext_vector_type(4))) float;
using bf8   = __attribute__((ext_vector_type(8))) short;   // 8 x bf16 (4 VGPRs)

__device__ __forceinline__ float bf2f(ushort u) {
    union { uint u; float f; } v; v.u = ((uint)u) << 16; return v.f;
}
__device__ __forceinline__ ushort f2bf(float f) {           // RNE
    union { float f; uint u; } v; v.f = f;
    uint u = v.u;
    u += 0x7fffu + ((u >> 16) & 1u);
    return (ushort)(u >> 16);
}
__device__ __forceinline__ ushort f2bf_trunc(float f) {     // truncate (1 VALU op)
    union { float f; uint u; } v; v.f = f;
    return (ushort)(v.u >> 16);
}

// ---------------------------------------------------------------- weights
// q-scale folds 1/sqrt(D) AND log2e (softmax uses exp2 directly)
__global__ __launch_bounds__(256) void prep_weights(
    const float* __restrict__ wq, const float* __restrict__ wk,
    const float* __restrict__ wv, const float* __restrict__ wg,
    const float* __restrict__ wb, const float* __restrict__ wo,
    ushort* __restrict__ Wcat, ushort* __restrict__ Wb, ushort* __restrict__ Wo)
{
    int t = blockIdx.x * 256 + threadIdx.x;    // 65536 threads
    const float scale = 0.17677669529663689f * LOG2E;
    float v;
    if (t < 16384)       v = wq[t] * scale;
    else if (t < 32768)  v = wk[t - 16384];
    else if (t < 49152)  v = wv[t - 32768];
    else                 v = wg[t - 49152];
    Wcat[t] = f2bf(v);
    if (t < 16384) Wo[t] = f2bf(wo[t]);
    if (t < 512)   Wb[t] = f2bf(wb[t]);
}

// ---------------------------------------------------------------- layernorm
__global__ __launch_bounds__(256) void ln_kernel(
    const float* __restrict__ x, const float* __restrict__ lnw,
    const float* __restrict__ lnb, ushort* __restrict__ xn)
{
    int wave = threadIdx.x >> 6, lane = threadIdx.x & 63;
    int p = blockIdx.x * 4 + wave;
    const float* xp = x + (size_t)p * C;
    float a0 = xp[lane], a1 = xp[lane + 64];
    float s = a0 + a1, ss = a0 * a0 + a1 * a1;
    #pragma unroll
    for (int m = 1; m < 64; m <<= 1) {
        s  += __shfl_xor(s, m, 64);
        ss += __shfl_xor(ss, m, 64);
    }
    float mean = s * (1.f / 128.f);
    float var  = ss * (1.f / 128.f) - mean * mean;
    float rstd = rsqrtf(var + LN_EPS);
    ushort* op = xn + (size_t)p * C;
    op[lane]      = f2bf((a0 - mean) * rstd * lnw[lane]      + lnb[lane]);
    op[lane + 64] = f2bf((a1 - mean) * rstd * lnw[lane + 64] + lnb[lane + 64]);
}

// ---------------------------------------------------------------- triangle bias
// Output: bf16 * LOG2E, pre-permuted into the attn fragment layout:
//   (h,q,k): qc=q>>4, quad=(q>>2)&3, r=q&3, n=k>>4, lrow=k&15
//   lane=quad*16+lrow, v=n*4+r, j=v>>3, m=v&7
//   idx = h*65536 + (((qc*8 + j)*64 + lane)*8 + m)
__global__ __launch_bounds__(256) void tri_kernel(
    const ushort* __restrict__ xn, const ushort* __restrict__ Wb,
    ushort* __restrict__ tri_p)
{
    __shared__ float wb[512];
    int t = threadIdx.x;
    wb[t]       = bf2f(Wb[t]);
    wb[t + 256] = bf2f(Wb[t + 256]);
    __syncthreads();
    int p = blockIdx.x * 256 + t;
    const ushort* xp = xn + (size_t)p * C;
    float acc0 = 0, acc1 = 0, acc2 = 0, acc3 = 0;
    #pragma unroll
    for (int c8 = 0; c8 < 16; c8++) {
        uint4 pk = ((const uint4*)xp)[c8];
        const ushort* u = (const ushort*)&pk;
        #pragma unroll
        for (int j = 0; j < 8; j++) {
            float xv = bf2f(u[j]);
            int c = c8 * 8 + j;
            acc0 += xv * wb[c];
            acc1 += xv * wb[128 + c];
            acc2 += xv * wb[256 + c];
            acc3 += xv * wb[384 + c];
        }
    }
    int q = p >> 8, k = p & 255;
    int qc = q >> 4, quad = (q >> 2) & 3, r = q & 3;
    int n = k >> 4, lrow = k & 15;
    int lane = quad * 16 + lrow;
    int v = n * 4 + r, j = v >> 3, m = v & 7;
    int base = ((qc * 8 + j) * 64 + lane) * 8 + m;
    tri_p[base]             = f2bf(acc0 * LOG2E);
    tri_p[65536 + base]     = f2bf(acc1 * LOG2E);
    tri_p[2 * 65536 + base] = f2bf(acc2 * LOG2E);
    tri_p[3 * 65536 + base] = f2bf(acc3 * LOG2E);
}

// ---------------------------------------------------------------- QKVG projection GEMM
// [65536,512] = Xn[65536,128] @ Wcat[512,128]^T, 128x128 tiles, grid (512,4).
// 512 threads (8 waves, 32x64 each). LDS tiles XOR-swizzled at 16B-chunk
// granularity (c8 ^ (row&7)) -> fragment reads are 2-way (free).
// nt: 0=q(scaled) 1=k 2=v(-> vbT transposed via LDS) 3=gate.
__global__ __launch_bounds__(512, 4) void proj_gemm(
    const ushort* __restrict__ xn, const ushort* __restrict__ Wcat,
    const float* __restrict__ bg,
    ushort* __restrict__ qb, ushort* __restrict__ kb,
    ushort* __restrict__ vbT, ushort* __restrict__ gate)
{
    __shared__ ushort At[128 * 128];   // 32 KB, swizzled
    __shared__ ushort Bt[128 * 128];   // 32 KB, swizzled (reused for V transpose)
    int mt = blockIdx.x;               // 0..511
    int nt = blockIdx.y;               // 0..3
    int t  = threadIdx.x;

    const uint4* Ag = (const uint4*)(xn   + (size_t)mt * 128 * C);
    const uint4* Bg = (const uint4*)(Wcat + (size_t)nt * 128 * C);
    #pragma unroll
    for (int ii = 0; ii < 4; ii++) {
        int idx = t + ii * 512;                  // 0..2047 chunks
        int row = idx >> 4, c8 = idx & 15;
        int sc = row * 16 + (c8 ^ (row & 7));
        ((uint4*)At)[sc] = Ag[idx];
        ((uint4*)Bt)[sc] = Bg[idx];
    }
    __syncthreads();

    int wave = t >> 6, lane = t & 63;
    int lrow = lane & 15, quad = lane >> 4;
    int wr = wave >> 1, wc = wave & 1;           // wr: 32-row strip, wc: 64-col strip

    f32x4 acc[2][4];
    #pragma unroll
    for (int mi = 0; mi < 2; mi++)
        #pragma unroll
        for (int ni = 0; ni < 4; ni++) acc[mi][ni] = (f32x4){0.f, 0.f, 0.f, 0.f};

    #pragma unroll
    for (int ks = 0; ks < 4; ks++) {
        int c8 = ks * 4 + quad;
        bf8 a[2], b[4];
        #pragma unroll
        for (int mi = 0; mi < 2; mi++) {
            int row = wr * 32 + mi * 16 + lrow;
            a[mi] = *(const bf8*)&At[(row * 16 + (c8 ^ (row & 7))) * 8];
        }
        #pragma unroll
        for (int ni = 0; ni < 4; ni++) {
            int row = wc * 64 + ni * 16 + lrow;
            b[ni] = *(const bf8*)&Bt[(row * 16 + (c8 ^ (row & 7))) * 8];
        }
        #pragma unroll
        for (int mi = 0; mi < 2; mi++)
            #pragma unroll
            for (int ni = 0; ni < 4; ni++)
                acc[mi][ni] = __builtin_amdgcn_mfma_f32_16x16x32_bf16(a[mi], b[ni], acc[mi][ni], 0, 0, 0);
    }

    if (nt == 2) {
        // transpose through Bt (done with B reads), then coalesced 16B vbT stores
        __syncthreads();
        #pragma unroll
        for (int mi = 0; mi < 2; mi++) {
            #pragma unroll
            for (int ni = 0; ni < 4; ni++) {
                int col = wc * 64 + ni * 16 + lrow;            // h*D+d, 0..127
                #pragma unroll
                for (int r = 0; r < 4; r++) {
                    int keyl = wr * 32 + mi * 16 + quad * 4 + r;   // 0..127
                    Bt[col * 128 + (keyl ^ (lrow << 3))] = f2bf(acc[mi][ni][r]);
                }
            }
        }
        __syncthreads();
        int i_row = mt >> 1;
        #pragma unroll
        for (int itr = 0; itr < 4; itr++) {
            int oidx = itr * 512 + t;          // 0..2047
            int col = oidx >> 4, kc = oidx & 15;
            bf8 val = *(const bf8*)&Bt[col * 128 + ((kc * 8) ^ ((col & 15) << 3))];
            *(bf8*)&vbT[(size_t)(i_row * 128 + col) * N + (mt & 1) * 128 + kc * 8] = val;
        }
    } else {
        ushort* dst = (nt == 0) ? qb : (nt == 1) ? kb : gate;
        bool gated = (nt == 3);
        #pragma unroll
        for (int mi = 0; mi < 2; mi++) {
            #pragma unroll
            for (int ni = 0; ni < 4; ni++) {
                int col = wc * 64 + ni * 16 + lrow;
                #pragma unroll
                for (int r = 0; r < 4; r++) {
                    int row = mt * 128 + wr * 32 + mi * 16 + quad * 4 + r;
                    float v = acc[mi][ni][r];
                    if (gated) v = 1.f / (1.f + __expf(-(v + bg[col])));
                    dst[(size_t)row * C + col] = f2bf(v);
                }
            }
        }
    }
}

// ---------------------------------------------------------------- attention
// grid (i=256, h=4), 512 threads = 8 waves, 2 q-chunks (16 rows) per wave.
// K/V staged coalesced into LDS in exact MFMA fragment order (conflict-free
// b128 reads). P per wave = one 128-key half (4 KB), flash-style two passes,
// O accumulated unnormalized. LDS = 64 KB -> 2 blocks/CU, 16 waves/CU.
__global__ __launch_bounds__(512, 4) void attn_kernel(
    const ushort* __restrict__ qb, const ushort* __restrict__ kb,
    const ushort* __restrict__ vbT, const ushort* __restrict__ tri_p,
    const float* __restrict__ mask, ushort* __restrict__ ob)
{
    __shared__ ushort Kf[8192];       // 16 KB: chunk c = kn*64+lane, 8 ushorts each
    __shared__ ushort Vf[8192];       // 16 KB: chunk c = nv*512+ks*64+lane, XOR-swizzled
    __shared__ ushort Pf[8][2048];    // 32 KB: per-wave 128-key half, A-frag order

    int i  = blockIdx.x;
    int h  = blockIdx.y;
    int t  = threadIdx.x;
    int wave = t >> 6, lane = t & 63;
    int lrow = lane & 15, quad = lane >> 4;

    // ---- stage K: global row-major (key, d) -> frag order, coalesced
    {
        const ushort* kt = kb + (size_t)(i * N) * C + h * D;
        #pragma unroll
        for (int it = 0; it < 2; it++) {
            int idx = it * 512 + t;                  // 0..1023
            int key = idx >> 2, d0 = (idx & 3) * 8;
            bf8 kv = *(const bf8*)(kt + (size_t)key * C + d0);
            int c = (idx >> 6) * 64 + (idx & 3) * 16 + ((idx >> 2) & 15);
            *(bf8*)&Kf[c * 8] = kv;
        }
    }
    // ---- stage V: vbT tile is contiguous 16 KB, coalesced; swizzled chunks
    {
        const ushort* vt = vbT + (size_t)((i * H + h) * D) * N;
        #pragma unroll
        for (int it = 0; it < 2; it++) {
            int idx = it * 512 + t;                  // 0..1023
            bf8 vv = *(const bf8*)(vt + idx * 8);
            int c = (idx >> 9) * 512 + ((idx >> 2) & 7) * 64 + (idx & 3) * 16 + ((idx >> 5) & 15);
            c ^= (c >> 6) & 7;
            *(bf8*)&Vf[c * 8] = vv;
        }
    }
    // mask bias per lane's 16 key-columns (log2e-folded)
    float mb[16];
    #pragma unroll
    for (int n = 0; n < 16; n++)
        mb[n] = (1e9f * LOG2E) * (mask[i * N + n * 16 + lrow] - 1.0f);
    __syncthreads();

    ushort* Pw = &Pf[wave][0];
    const ushort* trih = tri_p + (size_t)h * 65536;
    int pq = quad * 32 + (lrow & 7);       // P-write lane-invariant part
    int l3 = (lrow >> 3) & 1;

    #pragma unroll 1
    for (int cc = 0; cc < 2; cc++) {
        int qc = wave * 2 + cc;            // 0..15
        bf8 aq = *(const bf8*)(qb + (size_t)(i * N + qc * 16 + lrow) * C + h * D + quad * 8);
        float sum[4] = {0.f, 0.f, 0.f, 0.f};
        f32x4 o[2];
        o[0] = (f32x4){0.f, 0.f, 0.f, 0.f};
        o[1] = (f32x4){0.f, 0.f, 0.f, 0.f};

        #pragma unroll
        for (int half = 0; half < 2; half++) {
            // ---- S = Q K^T for 128 keys (8 MFMAs, K frags conflict-free from LDS)
            f32x4 s8[8];
            #pragma unroll
            for (int n8 = 0; n8 < 8; n8++) {
                bf8 kf = *(const bf8*)&Kf[((half * 8 + n8) * 64 + lane) * 8];
                s8[n8] = __builtin_amdgcn_mfma_f32_16x16x32_bf16(
                    aq, kf, (f32x4){0.f, 0.f, 0.f, 0.f}, 0, 0, 0);
            }
            // tri bias fragments: 4 x 16B coalesced loads (pre-permuted layout)
            const ushort* tp = trih + ((size_t)(qc * 8 + half * 4) * 64 + lane) * 8;
            bf8 tf[4];
            #pragma unroll
            for (int jj = 0; jj < 4; jj++)
                tf[jj] = *(const bf8*)(tp + jj * 512);

            // ---- exp2 softmax (no max-sub; logits tiny) + P write (A-frag order)
            #pragma unroll
            for (int n8 = 0; n8 < 8; n8++) {
                int pa = (n8 >> 1) * 512 + (((n8 << 1) + l3) & 3) * 128 + pq;
                #pragma unroll
                for (int r = 0; r < 4; r++) {
                    float tb = bf2f(((const ushort*)&tf[n8 >> 1])[((n8 & 1) << 2) + r]);
                    float e  = exp2f(s8[n8][r] + tb + mb[half * 8 + n8]);
                    sum[r]  += e;
                    Pw[pa + r * 8] = f2bf_trunc(e);
                }
            }
            // drain wave-private P writes (also guarantees prior P reads done)
            __asm__ volatile("s_waitcnt lgkmcnt(0)" ::: "memory");

            // ---- O += P V_half (K-dim 128 = 4 ks steps)
            #pragma unroll
            for (int ks = 0; ks < 4; ks++) {
                bf8 ap = *(const bf8*)&Pw[(ks * 64 + lane) * 8];
                int ksg = half * 4 + ks;
                #pragma unroll
                for (int nv = 0; nv < 2; nv++) {
                    int c = nv * 512 + ksg * 64 + (lane ^ (ksg & 7));
                    bf8 bv = *(const bf8*)&Vf[c * 8];
                    o[nv] = __builtin_amdgcn_mfma_f32_16x16x32_bf16(ap, bv, o[nv], 0, 0, 0);
                }
            }
        }
        // row sums -> 1/sum, normalize at epilogue
        #pragma unroll
        for (int r = 0; r < 4; r++) {
            float s = sum[r];
            s += __shfl_xor(s, 1, 64);
            s += __shfl_xor(s, 2, 64);
            s += __shfl_xor(s, 4, 64);
            s += __shfl_xor(s, 8, 64);
            sum[r] = 1.f / s;
        }
        #pragma unroll
        for (int nv = 0; nv < 2; nv++) {
            int d = nv * 16 + lrow;
            #pragma unroll
            for (int r = 0; r < 4; r++) {
                int qg = qc * 16 + quad * 4 + r;
                ob[(size_t)(i * N + qg) * C + h * D + d] = f2bf(o[nv][r] * sum[r]);
            }
        }
    }
}

// ---------------------------------------------------------------- gating + output proj
// out[65536,128] = (O .* gate)[65536,128] @ Wo[128,128]^T + b_o.
// 512 threads, 128x128 tile, XOR-swizzled LDS (same scheme as proj_gemm).
__global__ __launch_bounds__(512, 4) void out_gemm(
    const ushort* __restrict__ ob, const ushort* __restrict__ gate,
    const ushort* __restrict__ Wo, const float* __restrict__ bo,
    float* __restrict__ out)
{
    __shared__ ushort At[128 * 128];   // 32 KB, swizzled (gated O)
    __shared__ ushort Bt[128 * 128];   // 32 KB, swizzled (Wo)
    int mt = blockIdx.x;               // 0..511
    int t  = threadIdx.x;

    const uint4* Og = (const uint4*)(ob   + (size_t)mt * 128 * C);
    const uint4* Gg = (const uint4*)(gate + (size_t)mt * 128 * C);
    const uint4* Bg = (const uint4*)Wo;
    #pragma unroll
    for (int ii = 0; ii < 4; ii++) {
        int idx = t + ii * 512;                  // 0..2047 chunks
        int row = idx >> 4, c8 = idx & 15;
        int sc = row * 16 + (c8 ^ (row & 7));
        uint4 o4 = Og[idx], g4 = Gg[idx], r4;
        const ushort* os = (const ushort*)&o4;
        const ushort* gs = (const ushort*)&g4;
        ushort* rs = (ushort*)&r4;
        #pragma unroll
        for (int j = 0; j < 8; j++) rs[j] = f2bf(bf2f(os[j]) * bf2f(gs[j]));
        ((uint4*)At)[sc] = r4;
        ((uint4*)Bt)[sc] = Bg[idx];
    }
    __syncthreads();

    int wave = t >> 6, lane = t & 63;
    int lrow = lane & 15, quad = lane >> 4;
    int wr = wave >> 1, wc = wave & 1;

    f32x4 acc[2][4];
    #pragma unroll
    for (int mi = 0; mi < 2; mi++)
        #pragma unroll
        for (int ni = 0; ni < 4; ni++) acc[mi][ni] = (f32x4){0.f, 0.f, 0.f, 0.f};

    #pragma unroll
    for (int ks = 0; ks < 4; ks++) {
        int c8 = ks * 4 + quad;
        bf8 a[2], b[4];
        #pragma unroll
        for (int mi = 0; mi < 2; mi++) {
            int row = wr * 32 + mi * 16 + lrow;
            a[mi] = *(const bf8*)&At[(row * 16 + (c8 ^ (row & 7))) * 8];
        }
        #pragma unroll
        for (int ni = 0; ni < 4; ni++) {
            int row = wc * 64 + ni * 16 + lrow;
            b[ni] = *(const bf8*)&Bt[(row * 16 + (c8 ^ (row & 7))) * 8];
        }
        #pragma unroll
        for (int mi = 0; mi < 2; mi++)
            #pragma unroll
            for (int ni = 0; ni < 4; ni++)
                acc[mi][ni] = __builtin_amdgcn_mfma_f32_16x16x32_bf16(a[mi], b[ni], acc[mi][ni], 0, 0, 0);
    }

    #pragma unroll
    for (int mi = 0; mi < 2; mi++) {
        #pragma unroll
        for (int ni = 0; ni < 4; ni++) {
            int col = wc * 64 + ni * 16 + lrow;   // 0..127
            float bias = bo[col];
            #pragma unroll
            for (int r = 0; r < 4; r++) {
                int row = mt * 128 + wr * 32 + mi * 16 + quad * 4 + r;
                out[(size_t)row * C + col] = acc[mi][ni][r] + bias;
            }
        }
    }
}

// ---------------------------------------------------------------- launch
extern "C" void kernel_launch(void* const* d_in, const int* in_sizes, int n_in,
                              void* d_out, int out_size, void* d_ws, size_t ws_size,
                              hipStream_t stream)
{
    const float* x    = (const float*)d_in[0];
    const float* mask = (const float*)d_in[1];
    const float* lnw  = (const float*)d_in[2];
    const float* lnb  = (const float*)d_in[3];
    const float* wb   = (const float*)d_in[4];
    const float* wq   = (const float*)d_in[5];
    const float* wk   = (const float*)d_in[6];
    const float* wv   = (const float*)d_in[7];
    const float* wg   = (const float*)d_in[8];
    const float* bg   = (const float*)d_in[9];
    const float* wo   = (const float*)d_in[10];
    const float* bo   = (const float*)d_in[11];
    float* out = (float*)d_out;

    uintptr_t w = (uintptr_t)d_ws;
    ushort* xn    = (ushort*)w; w += (size_t)NP * C * 2;   // 16 MB
    ushort* qb    = (ushort*)w; w += (size_t)NP * C * 2;   // 16 MB
    ushort* kb    = (ushort*)w; w += (size_t)NP * C * 2;   // 16 MB
    ushort* vbT   = (ushort*)w; w += (size_t)NP * C * 2;   // 16 MB (transposed V)
    ushort* gate  = (ushort*)w; w += (size_t)NP * C * 2;   // 16 MB
    ushort* ob    = (ushort*)w; w += (size_t)NP * C * 2;   // 16 MB
    ushort* tri_p = (ushort*)w; w += (size_t)H * NP * 2;   // 0.5 MB
    ushort* Wcat  = (ushort*)w; w += 512 * 128 * 2;
    ushort* Wb    = (ushort*)w; w += 512 * 2;
    ushort* Wo    = (ushort*)w; w += 128 * 128 * 2;

    prep_weights<<<256, 256, 0, stream>>>(wq, wk, wv, wg, wb, wo, Wcat, Wb, Wo);
    ln_kernel<<<NP / 4, 256, 0, stream>>>(x, lnw, lnb, xn);
    tri_kernel<<<NP / 256, 256, 0, stream>>>(xn, Wb, tri_p);
    proj_gemm<<<dim3(NP / 128, 4), 512, 0, stream>>>(xn, Wcat, bg, qb, kb, vbT, gate);
    attn_kernel<<<dim3(N, H), 512, 0, stream>>>(qb, kb, vbT, tri_p, mask, ob);
    out_gemm<<<NP / 128, 512, 0, stream>>>(ob, gate, Wo, bo, out);
}